// Round 2
// baseline (573.061 us; speedup 1.0000x reference)
//
#include <hip/hip_runtime.h>
#include <hip/hip_bf16.h>

#define GN   50000
#define GE   1600000
#define GIN  32
#define GOUT 32
#define GK   25       // KS^DIM = 25
#define GKO  800      // K * OUT

// ---------------------------------------------------------------------------
// Stage 0: xW[n, k*32+o] = sum_i x[n,i] * W[k,i,o]
// GEMM: [50000 x 32] @ [32 x 800], tiled 64x64, 4x4 register blocking.
// A tile stored transposed in LDS so inner loop reads are float4 (b128).
// ---------------------------------------------------------------------------
__global__ __launch_bounds__(256) void xw_gemm(const float* __restrict__ X,
                                               const float* __restrict__ W,
                                               float* __restrict__ XW) {
    __shared__ float As[32][65];   // [k][row] transposed
    __shared__ float Bs[32][65];   // [k][col]
    const int n0  = blockIdx.y * 64;
    const int ko0 = blockIdx.x * 64;
    const int t   = threadIdx.x;

    // Load A tile transposed: thread reads float4 of X row, writes 4 rows of As
    for (int f = t; f < 512; f += 256) {
        int r  = f >> 3;
        int c4 = f & 7;
        int n  = n0 + r;
        float4 v = make_float4(0.f, 0.f, 0.f, 0.f);
        if (n < GN) v = reinterpret_cast<const float4*>(X + (size_t)n * GIN)[c4];
        As[c4 * 4 + 0][r] = v.x;
        As[c4 * 4 + 1][r] = v.y;
        As[c4 * 4 + 2][r] = v.z;
        As[c4 * 4 + 3][r] = v.w;
    }
    // Load B tile: 32 x 64; B(i, ko) = W[(ko>>5)*1024 + i*32 + (ko&31)]
    for (int f = t; f < 2048; f += 256) {
        int i  = f >> 6;
        int j  = f & 63;
        int ko = ko0 + j;
        float v = 0.f;
        if (ko < GKO) {
            int k = ko >> 5, o = ko & 31;
            v = W[k * 1024 + i * 32 + o];
        }
        Bs[i][j] = v;
    }
    __syncthreads();

    const int tx = t & 15, ty = t >> 4;
    float acc[4][4] = {};
#pragma unroll
    for (int k = 0; k < 32; ++k) {
        float4 a = *reinterpret_cast<const float4*>(&As[k][ty * 4]);
        float4 b = *reinterpret_cast<const float4*>(&Bs[k][tx * 4]);
        float av[4] = {a.x, a.y, a.z, a.w};
        float bv[4] = {b.x, b.y, b.z, b.w};
#pragma unroll
        for (int m = 0; m < 4; ++m)
#pragma unroll
            for (int j = 0; j < 4; ++j) acc[m][j] += av[m] * bv[j];
    }

#pragma unroll
    for (int m = 0; m < 4; ++m) {
        int n = n0 + ty * 4 + m;
        if (n >= GN) continue;
#pragma unroll
        for (int j = 0; j < 4; ++j) {
            int ko = ko0 + tx * 4 + j;
            if (ko < GKO) XW[(size_t)n * GKO + ko] = acc[m][j];
        }
    }
}

// ---------------------------------------------------------------------------
// Sort stage A: histogram of target nodes.
// ---------------------------------------------------------------------------
__global__ __launch_bounds__(256) void hist_kernel(const int* __restrict__ ei,
                                                   int* __restrict__ cnt) {
    int e = blockIdx.x * blockDim.x + threadIdx.x;
    if (e < GE) atomicAdd(&cnt[ei[e]], 1);
}

// ---------------------------------------------------------------------------
// Sort stage B: exclusive scan of cnt[GN] -> offs[GN+1], single block.
// ---------------------------------------------------------------------------
__global__ __launch_bounds__(1024) void scan_kernel(const int* __restrict__ cnt,
                                                    int* __restrict__ offs) {
    __shared__ int partial[1024];
    const int T = 1024;
    const int t = threadIdx.x;
    const int CH = (GN + T) / T;  // 49; 49*1024 = 50176 >= GN+1
    const int base = t * CH;

    int sum = 0;
    for (int i = 0; i < CH; ++i) {
        int idx = base + i;
        if (idx < GN) sum += cnt[idx];
    }
    partial[t] = sum;
    // Hillis-Steele inclusive scan
    for (int off = 1; off < T; off <<= 1) {
        __syncthreads();
        int v = (t >= off) ? partial[t - off] : 0;
        __syncthreads();
        partial[t] += v;
    }
    __syncthreads();

    int run = (t == 0) ? 0 : partial[t - 1];
    for (int i = 0; i < CH; ++i) {
        int idx = base + i;
        if (idx <= GN) {
            offs[idx] = run;
            if (idx < GN) run += cnt[idx];
        }
    }
}

// ---------------------------------------------------------------------------
// Sort stage C: scatter edge records into per-node buckets.
// rec = float4{ bitcast(col | i0<<16 | i1<<18), fr0, fr1, 0 }
// ---------------------------------------------------------------------------
__global__ __launch_bounds__(256) void bucket_kernel(const int* __restrict__ ei,
                                                     const float* __restrict__ pseudo,
                                                     const int* __restrict__ offs,
                                                     int* __restrict__ cursor,
                                                     float4* __restrict__ recs) {
    int e = blockIdx.x * blockDim.x + threadIdx.x;
    if (e >= GE) return;
    int row = ei[e];
    int col = ei[GE + e];
    float v0 = pseudo[2 * e] * 4.0f;
    float v1 = pseudo[2 * e + 1] * 4.0f;
    float f0 = floorf(v0), f1 = floorf(v1);
    int i0 = (int)f0, i1 = (int)f1;   // 0..3 (pseudo in [0,1))
    float fr0 = v0 - f0, fr1 = v1 - f1;

    int pos = offs[row] + atomicAdd(&cursor[row], 1);
    int packed = col | (i0 << 16) | (i1 << 18);
    recs[pos] = make_float4(__int_as_float(packed), fr0, fr1, 0.f);
}

// ---------------------------------------------------------------------------
// Stage 2: one 32-lane group per node; accumulate bucketed edges (no atomics),
// fused epilogue: out = acc/max(deg,1) + x@root + bias.
// ---------------------------------------------------------------------------
__global__ __launch_bounds__(256) void gather_finalize(const float4* __restrict__ recs,
                                                       const int* __restrict__ offs,
                                                       const float* __restrict__ xw,
                                                       const float* __restrict__ X,
                                                       const float* __restrict__ root,
                                                       const float* __restrict__ bias,
                                                       float* __restrict__ out) {
    int gid = blockIdx.x * blockDim.x + threadIdx.x;
    int n = gid >> 5;
    int o = gid & 31;
    if (n >= GN) return;

    int start = offs[n];
    int end   = offs[n + 1];

    float acc = 0.f;
    for (int j = start; j < end; ++j) {
        float4 r = recs[j];
        int packed = __float_as_int(r.x);
        int col = packed & 0xFFFF;
        int i0  = (packed >> 16) & 3;
        int i1  = (packed >> 18) & 3;
        float fr0 = r.y, fr1 = r.z;
        float g0 = 1.f - fr0, g1 = 1.f - fr1;

        const float* base = xw + (size_t)col * GKO + o;
        int w00 = (i0 + 5 * i1) * 32;
        acc += (g0  * g1 ) * base[w00];
        acc += (fr0 * g1 ) * base[w00 + 32];
        acc += (g0  * fr1) * base[w00 + 160];
        acc += (fr0 * fr1) * base[w00 + 192];
    }

    float d = fmaxf((float)(end - start), 1.0f);
    float res = acc / d + bias[o];
    float xv = X[(size_t)n * 32 + o];
#pragma unroll
    for (int i = 0; i < 32; ++i) res += __shfl(xv, i, 32) * root[i * 32 + o];
    out[(size_t)n * 32 + o] = res;
}

// ---------------------------------------------------------------------------
// Fallback path kernels (ws too small for bucketed path).
// ---------------------------------------------------------------------------
__global__ __launch_bounds__(256) void edge_scatter(const int* __restrict__ ei,
                                                    const float* __restrict__ pseudo,
                                                    const float* __restrict__ xw,
                                                    float* __restrict__ out,
                                                    float* __restrict__ deg) {
    int gid = blockIdx.x * blockDim.x + threadIdx.x;
    int e = gid >> 5;
    int o = gid & 31;
    if (e >= GE) return;
    int row = ei[e];
    int col = ei[GE + e];
    float v0 = pseudo[2 * e] * 4.0f, v1 = pseudo[2 * e + 1] * 4.0f;
    float f0 = floorf(v0), f1 = floorf(v1);
    float fr0 = v0 - f0, fr1 = v1 - f1;
    int i0 = (int)f0, i1 = (int)f1;
    const float* base = xw + (size_t)col * GKO + o;
    int w00 = (i0 + 5 * i1) * 32;
    float y = (1.f - fr0) * (1.f - fr1) * base[w00]
            + fr0 * (1.f - fr1) * base[w00 + 32]
            + (1.f - fr0) * fr1 * base[w00 + 160]
            + fr0 * fr1 * base[w00 + 192];
    atomicAdd(&out[(size_t)row * 32 + o], y);
    if (o == 0) atomicAdd(&deg[row], 1.0f);
}

__global__ __launch_bounds__(256) void finalize(const float* __restrict__ X,
                                                const float* __restrict__ root,
                                                const float* __restrict__ bias,
                                                const float* __restrict__ deg,
                                                float* __restrict__ out) {
    int t = blockIdx.x * blockDim.x + threadIdx.x;
    if (t >= GN * 32) return;
    int n = t >> 5, o = t & 31;
    float d = fmaxf(deg[n], 1.0f);
    float acc = out[t] / d + bias[o];
    float xv = X[(size_t)n * 32 + o];
#pragma unroll
    for (int i = 0; i < 32; ++i) acc += __shfl(xv, i, 32) * root[i * 32 + o];
    out[t] = acc;
}

extern "C" void kernel_launch(void* const* d_in, const int* in_sizes, int n_in,
                              void* d_out, int out_size, void* d_ws, size_t ws_size,
                              hipStream_t stream) {
    const float* x      = (const float*)d_in[0];
    const int*   ei     = (const int*)d_in[1];
    const float* pseudo = (const float*)d_in[2];
    const float* weight = (const float*)d_in[3];
    const float* root   = (const float*)d_in[4];
    const float* bias   = (const float*)d_in[5];
    float* out = (float*)d_out;

    const size_t xw_b   = (size_t)GN * GKO * sizeof(float);   // 160,000,000
    const size_t rec_b  = (size_t)GE * sizeof(float4);        //  25,600,000
    const size_t cnt_b  = (size_t)GN * sizeof(int);
    const size_t offs_b = (size_t)(GN + 1) * sizeof(int);
    const size_t cur_b  = (size_t)GN * sizeof(int);

    const int eb256 = (GE + 255) / 256;               // 1 thread / edge
    const int nb32  = (GN * 32 + 255) / 256;          // 32 lanes / node

    if (ws_size >= xw_b + rec_b + cnt_b + offs_b + cur_b) {
        char* p = (char*)d_ws;
        float*  xw     = (float*)p;                 p += xw_b;
        float4* recs   = (float4*)p;                p += rec_b;
        int*    cnt    = (int*)p;                   p += cnt_b;
        int*    offs   = (int*)p;                   p += offs_b;
        int*    cursor = (int*)p;

        hipMemsetAsync(cnt, 0, cnt_b, stream);
        hipMemsetAsync(cursor, 0, cur_b, stream);

        dim3 g0((GKO + 63) / 64, (GN + 63) / 64);
        xw_gemm<<<g0, 256, 0, stream>>>(x, weight, xw);

        hist_kernel<<<eb256, 256, 0, stream>>>(ei, cnt);
        scan_kernel<<<1, 1024, 0, stream>>>(cnt, offs);
        bucket_kernel<<<eb256, 256, 0, stream>>>(ei, pseudo, offs, cursor, recs);
        gather_finalize<<<nb32, 256, 0, stream>>>(recs, offs, xw, x, root, bias, out);
    } else if (ws_size >= xw_b + (size_t)GN * sizeof(float)) {
        float* xw  = (float*)d_ws;
        float* deg = (float*)((char*)d_ws + xw_b);
        hipMemsetAsync(d_out, 0, (size_t)GN * GOUT * sizeof(float), stream);
        hipMemsetAsync(deg, 0, (size_t)GN * sizeof(float), stream);

        dim3 g0((GKO + 63) / 64, (GN + 63) / 64);
        xw_gemm<<<g0, 256, 0, stream>>>(x, weight, xw);
        edge_scatter<<<(GE * 32 + 255) / 256, 256, 0, stream>>>(ei, pseudo, xw, out, deg);
        finalize<<<nb32, 256, 0, stream>>>(x, root, bias, deg, out);
    }
}

// Round 3
// 445.883 us; speedup vs baseline: 1.2852x; 1.2852x over previous
//
#include <hip/hip_runtime.h>
#include <hip/hip_bf16.h>

#define GN   50000
#define GE   1600000
#define GIN  32
#define GOUT 32
#define GK   25       // KS^DIM = 25
#define GKO  800      // K * OUT

// ---------------------------------------------------------------------------
// Stage 0: xW[n, k, o] = sum_i x[n,i] * W[k,i,o], stored as bf16.
// Register-resident W: thread (kp = t>>5, o = t&31) holds W[:, k, o] for
// k = kp + 8j (j<3) plus k=24 on kp==0 (zero-padded elsewhere).
// X strip (64 nodes) staged in LDS, read as broadcast float4.
// ---------------------------------------------------------------------------
__global__ __launch_bounds__(256) void xw_gemm2(const float* __restrict__ X,
                                                const float* __restrict__ W,
                                                __hip_bfloat16* __restrict__ XW) {
    __shared__ float xs[64][32];
    const int t  = threadIdx.x;
    const int n0 = blockIdx.x * 64;
    const int o  = t & 31;
    const int kp = t >> 5;   // 0..7

    // stage X strip: 512 float4 loads, coalesced
    for (int f = t; f < 512; f += 256) {
        int r = f >> 3, c4 = f & 7;
        int n = n0 + r;
        float4 v = make_float4(0.f, 0.f, 0.f, 0.f);
        if (n < GN) v = reinterpret_cast<const float4*>(X + (size_t)n * 32)[c4];
        *reinterpret_cast<float4*>(&xs[r][c4 * 4]) = v;
    }

    // W slices into registers
    float w[4][32];
#pragma unroll
    for (int j = 0; j < 3; ++j) {
        const float* wp = W + (size_t)(kp + 8 * j) * 1024 + o;
#pragma unroll
        for (int i = 0; i < 32; ++i) w[j][i] = wp[i * 32];
    }
    {
        const float* wp = W + (size_t)24 * 1024 + o;
#pragma unroll
        for (int i = 0; i < 32; ++i) w[3][i] = (kp == 0) ? wp[i * 32] : 0.f;
    }
    __syncthreads();

    const int nmax = (GN - n0 < 64) ? (GN - n0) : 64;
    for (int nn = 0; nn < nmax; ++nn) {
        float a0 = 0.f, a1 = 0.f, a2 = 0.f, a3 = 0.f;
#pragma unroll
        for (int c = 0; c < 8; ++c) {
            float4 xv = *reinterpret_cast<const float4*>(&xs[nn][c * 4]);
            a0 += xv.x * w[0][c*4+0]; a0 += xv.y * w[0][c*4+1];
            a0 += xv.z * w[0][c*4+2]; a0 += xv.w * w[0][c*4+3];
            a1 += xv.x * w[1][c*4+0]; a1 += xv.y * w[1][c*4+1];
            a1 += xv.z * w[1][c*4+2]; a1 += xv.w * w[1][c*4+3];
            a2 += xv.x * w[2][c*4+0]; a2 += xv.y * w[2][c*4+1];
            a2 += xv.z * w[2][c*4+2]; a2 += xv.w * w[2][c*4+3];
            a3 += xv.x * w[3][c*4+0]; a3 += xv.y * w[3][c*4+1];
            a3 += xv.z * w[3][c*4+2]; a3 += xv.w * w[3][c*4+3];
        }
        size_t nb = (size_t)(n0 + nn) * GKO + o;
        XW[nb + (kp     ) * 32] = __float2bfloat16(a0);
        XW[nb + (kp +  8) * 32] = __float2bfloat16(a1);
        XW[nb + (kp + 16) * 32] = __float2bfloat16(a2);
        if (kp == 0) XW[nb + 24 * 32] = __float2bfloat16(a3);
    }
}

// ---------------------------------------------------------------------------
// Sort stage A: histogram of target nodes.
// ---------------------------------------------------------------------------
__global__ __launch_bounds__(256) void hist_kernel(const int* __restrict__ ei,
                                                   int* __restrict__ cnt) {
    int e = blockIdx.x * blockDim.x + threadIdx.x;
    if (e < GE) atomicAdd(&cnt[ei[e]], 1);
}

// ---------------------------------------------------------------------------
// Sort stage B: exclusive scan of cnt[GN] -> offs[GN+1], single block.
// ---------------------------------------------------------------------------
__global__ __launch_bounds__(1024) void scan_kernel(const int* __restrict__ cnt,
                                                    int* __restrict__ offs) {
    __shared__ int partial[1024];
    const int T = 1024;
    const int t = threadIdx.x;
    const int CH = (GN + T) / T;  // 49; 49*1024 >= GN+1
    const int base = t * CH;

    int sum = 0;
    for (int i = 0; i < CH; ++i) {
        int idx = base + i;
        if (idx < GN) sum += cnt[idx];
    }
    partial[t] = sum;
    for (int off = 1; off < T; off <<= 1) {
        __syncthreads();
        int v = (t >= off) ? partial[t - off] : 0;
        __syncthreads();
        partial[t] += v;
    }
    __syncthreads();

    int run = (t == 0) ? 0 : partial[t - 1];
    for (int i = 0; i < CH; ++i) {
        int idx = base + i;
        if (idx <= GN) {
            offs[idx] = run;
            if (idx < GN) run += cnt[idx];
        }
    }
}

// ---------------------------------------------------------------------------
// Sort stage C: scatter edge records into per-node buckets.
// rec = float4{ bitcast(col | i0<<16 | i1<<18), fr0, fr1, 0 }
// ---------------------------------------------------------------------------
__global__ __launch_bounds__(256) void bucket_kernel(const int* __restrict__ ei,
                                                     const float* __restrict__ pseudo,
                                                     const int* __restrict__ offs,
                                                     int* __restrict__ cursor,
                                                     float4* __restrict__ recs) {
    int e = blockIdx.x * blockDim.x + threadIdx.x;
    if (e >= GE) return;
    int row = ei[e];
    int col = ei[GE + e];
    float v0 = pseudo[2 * e] * 4.0f;
    float v1 = pseudo[2 * e + 1] * 4.0f;
    float f0 = floorf(v0), f1 = floorf(v1);
    int i0 = (int)f0, i1 = (int)f1;   // 0..3
    float fr0 = v0 - f0, fr1 = v1 - f1;

    int pos = offs[row] + atomicAdd(&cursor[row], 1);
    int packed = col | (i0 << 16) | (i1 << 18);
    recs[pos] = make_float4(__int_as_float(packed), fr0, fr1, 0.f);
}

// ---------------------------------------------------------------------------
// Stage 2: one 32-lane group per node; accumulate bucketed edges (no atomics),
// fused epilogue: out = acc/max(deg,1) + x@root + bias. xW is bf16.
// ---------------------------------------------------------------------------
__global__ __launch_bounds__(256) void gather_finalize(const float4* __restrict__ recs,
                                                       const int* __restrict__ offs,
                                                       const __hip_bfloat16* __restrict__ xw,
                                                       const float* __restrict__ X,
                                                       const float* __restrict__ root,
                                                       const float* __restrict__ bias,
                                                       float* __restrict__ out) {
    int gid = blockIdx.x * blockDim.x + threadIdx.x;
    int n = gid >> 5;
    int o = gid & 31;
    if (n >= GN) return;

    int start = offs[n];
    int end   = offs[n + 1];

    float acc = 0.f;
    for (int j = start; j < end; ++j) {
        float4 r = recs[j];
        int packed = __float_as_int(r.x);
        int col = packed & 0xFFFF;
        int i0  = (packed >> 16) & 3;
        int i1  = (packed >> 18) & 3;
        float fr0 = r.y, fr1 = r.z;
        float g0 = 1.f - fr0, g1 = 1.f - fr1;

        const __hip_bfloat16* base = xw + (size_t)col * GKO + o;
        int w00 = (i0 + 5 * i1) * 32;
        acc += (g0  * g1 ) * __bfloat162float(base[w00]);
        acc += (fr0 * g1 ) * __bfloat162float(base[w00 + 32]);
        acc += (g0  * fr1) * __bfloat162float(base[w00 + 160]);
        acc += (fr0 * fr1) * __bfloat162float(base[w00 + 192]);
    }

    float d = fmaxf((float)(end - start), 1.0f);
    float res = acc / d + bias[o];
    float xv = X[(size_t)n * 32 + o];
#pragma unroll
    for (int i = 0; i < 32; ++i) res += __shfl(xv, i, 32) * root[i * 32 + o];
    out[(size_t)n * 32 + o] = res;
}

// ---------------------------------------------------------------------------
// Fallback path (ws too small for bucketed path): atomic scatter, bf16 xW.
// ---------------------------------------------------------------------------
__global__ __launch_bounds__(256) void edge_scatter(const int* __restrict__ ei,
                                                    const float* __restrict__ pseudo,
                                                    const __hip_bfloat16* __restrict__ xw,
                                                    float* __restrict__ out,
                                                    float* __restrict__ deg) {
    int gid = blockIdx.x * blockDim.x + threadIdx.x;
    int e = gid >> 5;
    int o = gid & 31;
    if (e >= GE) return;
    int row = ei[e];
    int col = ei[GE + e];
    float v0 = pseudo[2 * e] * 4.0f, v1 = pseudo[2 * e + 1] * 4.0f;
    float f0 = floorf(v0), f1 = floorf(v1);
    float fr0 = v0 - f0, fr1 = v1 - f1;
    int i0 = (int)f0, i1 = (int)f1;
    const __hip_bfloat16* base = xw + (size_t)col * GKO + o;
    int w00 = (i0 + 5 * i1) * 32;
    float y = (1.f - fr0) * (1.f - fr1) * __bfloat162float(base[w00])
            + fr0 * (1.f - fr1) * __bfloat162float(base[w00 + 32])
            + (1.f - fr0) * fr1 * __bfloat162float(base[w00 + 160])
            + fr0 * fr1 * __bfloat162float(base[w00 + 192]);
    atomicAdd(&out[(size_t)row * 32 + o], y);
    if (o == 0) atomicAdd(&deg[row], 1.0f);
}

__global__ __launch_bounds__(256) void finalize(const float* __restrict__ X,
                                                const float* __restrict__ root,
                                                const float* __restrict__ bias,
                                                const float* __restrict__ deg,
                                                float* __restrict__ out) {
    int t = blockIdx.x * blockDim.x + threadIdx.x;
    if (t >= GN * 32) return;
    int n = t >> 5, o = t & 31;
    float d = fmaxf(deg[n], 1.0f);
    float acc = out[t] / d + bias[o];
    float xv = X[(size_t)n * 32 + o];
#pragma unroll
    for (int i = 0; i < 32; ++i) acc += __shfl(xv, i, 32) * root[i * 32 + o];
    out[t] = acc;
}

extern "C" void kernel_launch(void* const* d_in, const int* in_sizes, int n_in,
                              void* d_out, int out_size, void* d_ws, size_t ws_size,
                              hipStream_t stream) {
    const float* x      = (const float*)d_in[0];
    const int*   ei     = (const int*)d_in[1];
    const float* pseudo = (const float*)d_in[2];
    const float* weight = (const float*)d_in[3];
    const float* root   = (const float*)d_in[4];
    const float* bias   = (const float*)d_in[5];
    float* out = (float*)d_out;

    const size_t xw_b   = (size_t)GN * GKO * sizeof(__hip_bfloat16);  // 80 MB
    const size_t rec_b  = (size_t)GE * sizeof(float4);                // 25.6 MB
    const size_t cnt_b  = (size_t)GN * sizeof(int);
    const size_t offs_b = (size_t)(GN + 1) * sizeof(int);
    const size_t cur_b  = (size_t)GN * sizeof(int);

    const int eb256 = (GE + 255) / 256;
    const int nb32  = (GN * 32 + 255) / 256;
    const int gemm_blocks = (GN + 63) / 64;

    if (ws_size >= xw_b + rec_b + cnt_b + offs_b + cur_b) {
        char* p = (char*)d_ws;
        __hip_bfloat16* xw = (__hip_bfloat16*)p;    p += xw_b;
        float4* recs   = (float4*)p;                p += rec_b;
        int*    cnt    = (int*)p;                   p += cnt_b;
        int*    offs   = (int*)p;                   p += offs_b;
        int*    cursor = (int*)p;

        hipMemsetAsync(cnt, 0, cnt_b, stream);
        hipMemsetAsync(cursor, 0, cur_b, stream);

        xw_gemm2<<<gemm_blocks, 256, 0, stream>>>(x, weight, xw);

        hist_kernel<<<eb256, 256, 0, stream>>>(ei, cnt);
        scan_kernel<<<1, 1024, 0, stream>>>(cnt, offs);
        bucket_kernel<<<eb256, 256, 0, stream>>>(ei, pseudo, offs, cursor, recs);
        gather_finalize<<<nb32, 256, 0, stream>>>(recs, offs, xw, x, root, bias, out);
    } else if (ws_size >= xw_b + (size_t)GN * sizeof(float)) {
        __hip_bfloat16* xw = (__hip_bfloat16*)d_ws;
        float* deg = (float*)((char*)d_ws + xw_b);
        hipMemsetAsync(d_out, 0, (size_t)GN * GOUT * sizeof(float), stream);
        hipMemsetAsync(deg, 0, (size_t)GN * sizeof(float), stream);

        xw_gemm2<<<gemm_blocks, 256, 0, stream>>>(x, weight, xw);
        edge_scatter<<<(GE * 32 + 255) / 256, 256, 0, stream>>>(ei, pseudo, xw, out, deg);
        finalize<<<nb32, 256, 0, stream>>>(x, root, bias, deg, out);
    }
}

// Round 4
// 322.165 us; speedup vs baseline: 1.7788x; 1.3840x over previous
//
#include <hip/hip_runtime.h>
#include <hip/hip_bf16.h>

#define GN   50000
#define GE   1600000
#define GIN  32
#define GOUT 32
#define GK   25
#define GKO  800
#define SCAN_NB 196   // 196*256 = 50176 >= GN+1

// ---------------------------------------------------------------------------
// Stage 0: xW[n, k, o] = sum_i x[n,i] * W[k,i,o], stored bf16.
// ---------------------------------------------------------------------------
__global__ __launch_bounds__(256) void xw_gemm2(const float* __restrict__ X,
                                                const float* __restrict__ W,
                                                __hip_bfloat16* __restrict__ XW) {
    __shared__ float xs[64][32];
    const int t  = threadIdx.x;
    const int n0 = blockIdx.x * 64;
    const int o  = t & 31;
    const int kp = t >> 5;   // 0..7

    for (int f = t; f < 512; f += 256) {
        int r = f >> 3, c4 = f & 7;
        int n = n0 + r;
        float4 v = make_float4(0.f, 0.f, 0.f, 0.f);
        if (n < GN) v = reinterpret_cast<const float4*>(X + (size_t)n * 32)[c4];
        *reinterpret_cast<float4*>(&xs[r][c4 * 4]) = v;
    }

    float w[4][32];
#pragma unroll
    for (int j = 0; j < 3; ++j) {
        const float* wp = W + (size_t)(kp + 8 * j) * 1024 + o;
#pragma unroll
        for (int i = 0; i < 32; ++i) w[j][i] = wp[i * 32];
    }
    {
        const float* wp = W + (size_t)24 * 1024 + o;
#pragma unroll
        for (int i = 0; i < 32; ++i) w[3][i] = (kp == 0) ? wp[i * 32] : 0.f;
    }
    __syncthreads();

    const int nmax = (GN - n0 < 64) ? (GN - n0) : 64;
    for (int nn = 0; nn < nmax; ++nn) {
        float a0 = 0.f, a1 = 0.f, a2 = 0.f, a3 = 0.f;
#pragma unroll
        for (int c = 0; c < 8; ++c) {
            float4 xv = *reinterpret_cast<const float4*>(&xs[nn][c * 4]);
            a0 += xv.x * w[0][c*4+0]; a0 += xv.y * w[0][c*4+1];
            a0 += xv.z * w[0][c*4+2]; a0 += xv.w * w[0][c*4+3];
            a1 += xv.x * w[1][c*4+0]; a1 += xv.y * w[1][c*4+1];
            a1 += xv.z * w[1][c*4+2]; a1 += xv.w * w[1][c*4+3];
            a2 += xv.x * w[2][c*4+0]; a2 += xv.y * w[2][c*4+1];
            a2 += xv.z * w[2][c*4+2]; a2 += xv.w * w[2][c*4+3];
            a3 += xv.x * w[3][c*4+0]; a3 += xv.y * w[3][c*4+1];
            a3 += xv.z * w[3][c*4+2]; a3 += xv.w * w[3][c*4+3];
        }
        size_t nb = (size_t)(n0 + nn) * GKO + o;
        XW[nb + (kp     ) * 32] = __float2bfloat16(a0);
        XW[nb + (kp +  8) * 32] = __float2bfloat16(a1);
        XW[nb + (kp + 16) * 32] = __float2bfloat16(a2);
        if (kp == 0) XW[nb + 24 * 32] = __float2bfloat16(a3);
    }
}

// ---------------------------------------------------------------------------
// Sort A: histogram of target nodes, 4 edges/thread.
// ---------------------------------------------------------------------------
__global__ __launch_bounds__(256) void hist4(const int* __restrict__ ei,
                                             int* __restrict__ cnt) {
    int t = blockIdx.x * 256 + threadIdx.x;
    int e0 = t * 4;
    if (e0 >= GE) return;
    int4 r = *reinterpret_cast<const int4*>(ei + e0);
    atomicAdd(&cnt[r.x], 1);
    atomicAdd(&cnt[r.y], 1);
    atomicAdd(&cnt[r.z], 1);
    atomicAdd(&cnt[r.w], 1);
}

// ---------------------------------------------------------------------------
// Sort B: 3-phase parallel exclusive scan of cnt[GN] -> offs[GN+1].
// ---------------------------------------------------------------------------
__global__ __launch_bounds__(256) void scan_a(const int* __restrict__ cnt,
                                              int* __restrict__ bsum) {
    __shared__ int s[256];
    int t = threadIdx.x;
    int i = blockIdx.x * 256 + t;
    s[t] = (i < GN) ? cnt[i] : 0;
    __syncthreads();
    for (int off = 128; off > 0; off >>= 1) {
        if (t < off) s[t] += s[t + off];
        __syncthreads();
    }
    if (t == 0) bsum[blockIdx.x] = s[0];
}

__global__ __launch_bounds__(256) void scan_b(const int* __restrict__ bsum,
                                              int* __restrict__ boff) {
    __shared__ int s[256];
    int t = threadIdx.x;
    s[t] = (t < SCAN_NB) ? bsum[t] : 0;
    for (int off = 1; off < 256; off <<= 1) {
        __syncthreads();
        int v = (t >= off) ? s[t - off] : 0;
        __syncthreads();
        s[t] += v;
    }
    __syncthreads();
    if (t < SCAN_NB) boff[t] = (t == 0) ? 0 : s[t - 1];
}

__global__ __launch_bounds__(256) void scan_c(const int* __restrict__ cnt,
                                              const int* __restrict__ boff,
                                              int* __restrict__ offs) {
    __shared__ int s[256];
    int t = threadIdx.x;
    int i = blockIdx.x * 256 + t;
    int c = (i < GN) ? cnt[i] : 0;
    s[t] = c;
    for (int off = 1; off < 256; off <<= 1) {
        __syncthreads();
        int v = (t >= off) ? s[t - off] : 0;
        __syncthreads();
        s[t] += v;
    }
    __syncthreads();
    int incl = s[t];
    int base = boff[blockIdx.x];
    if (i < GN) offs[i] = base + incl - c;
    if (i == GN - 1) offs[GN] = base + incl;
}

// ---------------------------------------------------------------------------
// Sort C: scatter 8-B edge records into buckets. atomicSub leaves cnt == 0
// (self-restoring for next replay). Record: w0 = col | i0<<17 | i1<<19;
// w1 = ufix16(fr0) | ufix16(fr1)<<16.
// ---------------------------------------------------------------------------
__device__ __forceinline__ uint2 pack_edge(int col, float p0, float p1) {
    float v0 = p0 * 4.f, v1 = p1 * 4.f;
    float f0 = floorf(v0), f1 = floorf(v1);
    int i0 = (int)f0, i1 = (int)f1;   // 0..3
    unsigned u0 = (unsigned)__float2int_rn((v0 - f0) * 65536.f);
    unsigned u1 = (unsigned)__float2int_rn((v1 - f1) * 65536.f);
    if (u0 > 65535u) u0 = 65535u;
    if (u1 > 65535u) u1 = 65535u;
    uint2 r;
    r.x = (unsigned)col | ((unsigned)i0 << 17) | ((unsigned)i1 << 19);
    r.y = u0 | (u1 << 16);
    return r;
}

__global__ __launch_bounds__(256) void bucket2(const int* __restrict__ ei,
                                               const float* __restrict__ pseudo,
                                               const int* __restrict__ offs,
                                               int* __restrict__ cnt,
                                               uint2* __restrict__ recs) {
    int t = blockIdx.x * 256 + threadIdx.x;
    int e0 = t * 2;
    if (e0 >= GE) return;
    int2 rows = *reinterpret_cast<const int2*>(ei + e0);
    int2 cols = *reinterpret_cast<const int2*>(ei + GE + e0);
    float4 ps = *reinterpret_cast<const float4*>(pseudo + 2 * e0);

    int pa = offs[rows.x] + atomicSub(&cnt[rows.x], 1) - 1;
    recs[pa] = pack_edge(cols.x, ps.x, ps.y);
    int pb = offs[rows.y] + atomicSub(&cnt[rows.y], 1) - 1;
    recs[pb] = pack_edge(cols.y, ps.z, ps.w);
}

// ---------------------------------------------------------------------------
// Stage 2: one 32-lane group per node, 4-edge unrolled gather, fused epilogue.
// ---------------------------------------------------------------------------
__device__ __forceinline__ float edge_term(uint2 r,
                                           const __hip_bfloat16* __restrict__ xw,
                                           int o) {
    unsigned w0 = r.x;
    unsigned col = w0 & 0x1FFFFu;
    int i0 = (w0 >> 17) & 3;
    int i1 = (w0 >> 19) & 3;
    float fr0 = (float)(r.y & 0xFFFFu) * (1.f / 65536.f);
    float fr1 = (float)(r.y >> 16)     * (1.f / 65536.f);
    float g0 = 1.f - fr0, g1 = 1.f - fr1;
    const __hip_bfloat16* base = xw + col * 800u + (unsigned)((i0 + 5 * i1) * 32 + o);
    float v00 = __bfloat162float(base[0]);
    float v01 = __bfloat162float(base[32]);
    float v10 = __bfloat162float(base[160]);
    float v11 = __bfloat162float(base[192]);
    return (g0 * g1) * v00 + (fr0 * g1) * v01 + (g0 * fr1) * v10 + (fr0 * fr1) * v11;
}

__global__ __launch_bounds__(256) void gather_finalize(const uint2* __restrict__ recs,
                                                       const int* __restrict__ offs,
                                                       const __hip_bfloat16* __restrict__ xw,
                                                       const float* __restrict__ X,
                                                       const float* __restrict__ root,
                                                       const float* __restrict__ bias,
                                                       float* __restrict__ out) {
    int gid = blockIdx.x * 256 + threadIdx.x;
    int n = gid >> 5;
    int o = gid & 31;
    if (n >= GN) return;

    int start = offs[n];
    int end   = offs[n + 1];

    float a0 = 0.f, a1 = 0.f, a2 = 0.f, a3 = 0.f;
    int j = start;
    for (; j + 4 <= end; j += 4) {
        uint2 r0 = recs[j];
        uint2 r1 = recs[j + 1];
        uint2 r2 = recs[j + 2];
        uint2 r3 = recs[j + 3];
        a0 += edge_term(r0, xw, o);
        a1 += edge_term(r1, xw, o);
        a2 += edge_term(r2, xw, o);
        a3 += edge_term(r3, xw, o);
    }
    for (; j < end; ++j) a0 += edge_term(recs[j], xw, o);
    float acc = (a0 + a1) + (a2 + a3);

    float d = fmaxf((float)(end - start), 1.0f);
    float res = acc / d + bias[o];
    float xv = X[(size_t)n * 32 + o];
#pragma unroll
    for (int i = 0; i < 32; ++i) res += __shfl(xv, i, 32) * root[i * 32 + o];
    out[(size_t)n * 32 + o] = res;
}

// ---------------------------------------------------------------------------
// Fallback path (ws too small): atomic scatter from bf16 xw.
// ---------------------------------------------------------------------------
__global__ __launch_bounds__(256) void edge_scatter(const int* __restrict__ ei,
                                                    const float* __restrict__ pseudo,
                                                    const __hip_bfloat16* __restrict__ xw,
                                                    float* __restrict__ out,
                                                    float* __restrict__ deg) {
    int gid = blockIdx.x * blockDim.x + threadIdx.x;
    int e = gid >> 5;
    int o = gid & 31;
    if (e >= GE) return;
    int row = ei[e];
    int col = ei[GE + e];
    float v0 = pseudo[2 * e] * 4.0f, v1 = pseudo[2 * e + 1] * 4.0f;
    float f0 = floorf(v0), f1 = floorf(v1);
    float fr0 = v0 - f0, fr1 = v1 - f1;
    int i0 = (int)f0, i1 = (int)f1;
    const __hip_bfloat16* base = xw + (size_t)col * GKO + o;
    int w00 = (i0 + 5 * i1) * 32;
    float y = (1.f - fr0) * (1.f - fr1) * __bfloat162float(base[w00])
            + fr0 * (1.f - fr1) * __bfloat162float(base[w00 + 32])
            + (1.f - fr0) * fr1 * __bfloat162float(base[w00 + 160])
            + fr0 * fr1 * __bfloat162float(base[w00 + 192]);
    atomicAdd(&out[(size_t)row * 32 + o], y);
    if (o == 0) atomicAdd(&deg[row], 1.0f);
}

__global__ __launch_bounds__(256) void finalize(const float* __restrict__ X,
                                                const float* __restrict__ root,
                                                const float* __restrict__ bias,
                                                const float* __restrict__ deg,
                                                float* __restrict__ out) {
    int t = blockIdx.x * blockDim.x + threadIdx.x;
    if (t >= GN * 32) return;
    int n = t >> 5, o = t & 31;
    float d = fmaxf(deg[n], 1.0f);
    float acc = out[t] / d + bias[o];
    float xv = X[(size_t)n * 32 + o];
#pragma unroll
    for (int i = 0; i < 32; ++i) acc += __shfl(xv, i, 32) * root[i * 32 + o];
    out[t] = acc;
}

extern "C" void kernel_launch(void* const* d_in, const int* in_sizes, int n_in,
                              void* d_out, int out_size, void* d_ws, size_t ws_size,
                              hipStream_t stream) {
    const float* x      = (const float*)d_in[0];
    const int*   ei     = (const int*)d_in[1];
    const float* pseudo = (const float*)d_in[2];
    const float* weight = (const float*)d_in[3];
    const float* root   = (const float*)d_in[4];
    const float* bias   = (const float*)d_in[5];
    float* out = (float*)d_out;

    const size_t xw_b   = (size_t)GN * GKO * 2;          // 80,000,000
    const size_t rec_b  = (size_t)GE * 8;                // 12,800,000
    const size_t cnt_b  = (size_t)GN * 4;                //    200,000
    const size_t offs_b = ((size_t)(GN + 1) * 4 + 15) & ~(size_t)15;
    const size_t bs_b   = (size_t)SCAN_NB * 4;           // 784 (16-mult)

    const int gemm_blocks = (GN + 63) / 64;
    const int nb32 = (GN * 32 + 255) / 256;

    if (ws_size >= xw_b + rec_b + cnt_b + offs_b + 2 * bs_b) {
        char* p = (char*)d_ws;
        __hip_bfloat16* xw = (__hip_bfloat16*)p;  p += xw_b;
        uint2* recs = (uint2*)p;                  p += rec_b;
        int*   cnt  = (int*)p;                    p += cnt_b;
        int*   offs = (int*)p;                    p += offs_b;
        int*   bsum = (int*)p;                    p += bs_b;
        int*   boff = (int*)p;

        hipMemsetAsync(cnt, 0, cnt_b, stream);

        xw_gemm2<<<gemm_blocks, 256, 0, stream>>>(x, weight, xw);

        hist4<<<(GE / 4 + 255) / 256, 256, 0, stream>>>(ei, cnt);
        scan_a<<<SCAN_NB, 256, 0, stream>>>(cnt, bsum);
        scan_b<<<1, 256, 0, stream>>>(bsum, boff);
        scan_c<<<SCAN_NB, 256, 0, stream>>>(cnt, boff, offs);
        bucket2<<<(GE / 2 + 255) / 256, 256, 0, stream>>>(ei, pseudo, offs, cnt, recs);
        gather_finalize<<<nb32, 256, 0, stream>>>(recs, offs, xw, x, root, bias, out);
    } else if (ws_size >= xw_b + (size_t)GN * sizeof(float)) {
        __hip_bfloat16* xw = (__hip_bfloat16*)d_ws;
        float* deg = (float*)((char*)d_ws + xw_b);
        hipMemsetAsync(d_out, 0, (size_t)GN * GOUT * sizeof(float), stream);
        hipMemsetAsync(deg, 0, (size_t)GN * sizeof(float), stream);

        xw_gemm2<<<gemm_blocks, 256, 0, stream>>>(x, weight, xw);
        edge_scatter<<<(GE * 32 + 255) / 256, 256, 0, stream>>>(ei, pseudo, xw, out, deg);
        finalize<<<nb32, 256, 0, stream>>>(x, root, bias, deg, out);
    }
}

// Round 5
// 293.456 us; speedup vs baseline: 1.9528x; 1.0978x over previous
//
#include <hip/hip_runtime.h>
#include <hip/hip_bf16.h>

#define GN   50000
#define GE   1600000
#define GIN  32
#define GOUT 32
#define GK   25
#define GKO  800
#define SCAN_NB 196      // 196*256 = 50176 >= GN+1
#define NGRP 8           // XCD groups
#define NPG  6250        // nodes per group = GN/NGRP
#define BPG  128         // bucket blocks per group

// ---------------------------------------------------------------------------
// Stage 0: xW[n,k,o] = sum_i x[n,i]*W[k,i,o] (bf16 out) + fused row histogram.
// ---------------------------------------------------------------------------
__global__ __launch_bounds__(256) void xw_gemm2(const float* __restrict__ X,
                                                const float* __restrict__ W,
                                                __hip_bfloat16* __restrict__ XW,
                                                const int* __restrict__ ei,
                                                int* __restrict__ cnt) {
    // fused histogram: block covers 2048 edges (782*2048 >= GE)
    if (cnt != nullptr) {
#pragma unroll
        for (int h = 0; h < 2; ++h) {
            int e = blockIdx.x * 2048 + h * 1024 + threadIdx.x * 4;
            if (e + 3 < GE) {
                int4 r = *reinterpret_cast<const int4*>(ei + e);
                atomicAdd(&cnt[r.x], 1);
                atomicAdd(&cnt[r.y], 1);
                atomicAdd(&cnt[r.z], 1);
                atomicAdd(&cnt[r.w], 1);
            } else if (e < GE) {
                for (int q = e; q < GE; ++q) atomicAdd(&cnt[ei[q]], 1);
            }
        }
    }

    __shared__ float xs[64][32];
    const int t  = threadIdx.x;
    const int n0 = blockIdx.x * 64;
    const int o  = t & 31;
    const int kp = t >> 5;   // 0..7

    for (int f = t; f < 512; f += 256) {
        int r = f >> 3, c4 = f & 7;
        int n = n0 + r;
        float4 v = make_float4(0.f, 0.f, 0.f, 0.f);
        if (n < GN) v = reinterpret_cast<const float4*>(X + (size_t)n * 32)[c4];
        *reinterpret_cast<float4*>(&xs[r][c4 * 4]) = v;
    }

    float w[4][32];
#pragma unroll
    for (int j = 0; j < 3; ++j) {
        const float* wp = W + (size_t)(kp + 8 * j) * 1024 + o;
#pragma unroll
        for (int i = 0; i < 32; ++i) w[j][i] = wp[i * 32];
    }
    {
        const float* wp = W + (size_t)24 * 1024 + o;
#pragma unroll
        for (int i = 0; i < 32; ++i) w[3][i] = (kp == 0) ? wp[i * 32] : 0.f;
    }
    __syncthreads();

    const int nmax = (GN - n0 < 64) ? (GN - n0) : 64;
    for (int nn = 0; nn < nmax; ++nn) {
        float a0 = 0.f, a1 = 0.f, a2 = 0.f, a3 = 0.f;
#pragma unroll
        for (int c = 0; c < 8; ++c) {
            float4 xv = *reinterpret_cast<const float4*>(&xs[nn][c * 4]);
            a0 += xv.x * w[0][c*4+0]; a0 += xv.y * w[0][c*4+1];
            a0 += xv.z * w[0][c*4+2]; a0 += xv.w * w[0][c*4+3];
            a1 += xv.x * w[1][c*4+0]; a1 += xv.y * w[1][c*4+1];
            a1 += xv.z * w[1][c*4+2]; a1 += xv.w * w[1][c*4+3];
            a2 += xv.x * w[2][c*4+0]; a2 += xv.y * w[2][c*4+1];
            a2 += xv.z * w[2][c*4+2]; a2 += xv.w * w[2][c*4+3];
            a3 += xv.x * w[3][c*4+0]; a3 += xv.y * w[3][c*4+1];
            a3 += xv.z * w[3][c*4+2]; a3 += xv.w * w[3][c*4+3];
        }
        size_t nb = (size_t)(n0 + nn) * GKO + o;
        XW[nb + (kp     ) * 32] = __float2bfloat16(a0);
        XW[nb + (kp +  8) * 32] = __float2bfloat16(a1);
        XW[nb + (kp + 16) * 32] = __float2bfloat16(a2);
        if (kp == 0) XW[nb + 24 * 32] = __float2bfloat16(a3);
    }
}

// ---------------------------------------------------------------------------
// Scan: cnt[GN] -> offs[GN+1] (exclusive) and cur[GN] (= end offsets).
// ---------------------------------------------------------------------------
__global__ __launch_bounds__(256) void scan_a(const int* __restrict__ cnt,
                                              int* __restrict__ bsum) {
    __shared__ int s[256];
    int t = threadIdx.x;
    int i = blockIdx.x * 256 + t;
    s[t] = (i < GN) ? cnt[i] : 0;
    __syncthreads();
    for (int off = 128; off > 0; off >>= 1) {
        if (t < off) s[t] += s[t + off];
        __syncthreads();
    }
    if (t == 0) bsum[blockIdx.x] = s[0];
}

__global__ __launch_bounds__(256) void scan_b(const int* __restrict__ bsum,
                                              int* __restrict__ boff) {
    __shared__ int s[256];
    int t = threadIdx.x;
    s[t] = (t < SCAN_NB) ? bsum[t] : 0;
    for (int off = 1; off < 256; off <<= 1) {
        __syncthreads();
        int v = (t >= off) ? s[t - off] : 0;
        __syncthreads();
        s[t] += v;
    }
    __syncthreads();
    if (t < SCAN_NB) boff[t] = (t == 0) ? 0 : s[t - 1];
}

__global__ __launch_bounds__(256) void scan_c(const int* __restrict__ cnt,
                                              const int* __restrict__ boff,
                                              int* __restrict__ offs,
                                              int* __restrict__ cur) {
    __shared__ int s[256];
    int t = threadIdx.x;
    int i = blockIdx.x * 256 + t;
    int c = (i < GN) ? cnt[i] : 0;
    s[t] = c;
    for (int off = 1; off < 256; off <<= 1) {
        __syncthreads();
        int v = (t >= off) ? s[t - off] : 0;
        __syncthreads();
        s[t] += v;
    }
    __syncthreads();
    int incl = s[t];
    int base = boff[blockIdx.x];
    if (i < GN) {
        offs[i] = base + incl - c;
        cur[i]  = base + incl;
    }
    if (i == GN - 1) offs[GN] = base + incl;
}

// ---------------------------------------------------------------------------
// Bucket scatter, XCD-ownership version: group grp = blockIdx&7 (round-robin
// XCD mapping) owns node range [grp*NPG,(grp+1)*NPG). Every group scans all
// edge rows but writes only its own range -> recs/cursor lines single-XCD.
// Record: w0 = col | i0<<17 | i1<<19 ; w1 = ufix16(fr0) | ufix16(fr1)<<16.
// ---------------------------------------------------------------------------
__device__ __forceinline__ uint2 pack_edge(int col, float p0, float p1) {
    float v0 = p0 * 4.f, v1 = p1 * 4.f;
    float f0 = floorf(v0), f1 = floorf(v1);
    int i0 = (int)f0, i1 = (int)f1;   // 0..3
    unsigned u0 = (unsigned)__float2int_rn((v0 - f0) * 65536.f);
    unsigned u1 = (unsigned)__float2int_rn((v1 - f1) * 65536.f);
    if (u0 > 65535u) u0 = 65535u;
    if (u1 > 65535u) u1 = 65535u;
    uint2 r;
    r.x = (unsigned)col | ((unsigned)i0 << 17) | ((unsigned)i1 << 19);
    r.y = u0 | (u1 << 16);
    return r;
}

__global__ __launch_bounds__(256) void bucket_x(const int* __restrict__ ei,
                                                const float* __restrict__ pseudo,
                                                int* __restrict__ cur,
                                                uint2* __restrict__ recs) {
    const int grp = blockIdx.x & (NGRP - 1);
    const int idx = blockIdx.x >> 3;
    const int lo = grp * NPG, hi = lo + NPG;
    const int stride = BPG * 256;

    for (int tp = idx * 256 + threadIdx.x; tp * 2 < GE; tp += stride) {
        int e0 = tp * 2;
        int2 rows = *reinterpret_cast<const int2*>(ei + e0);
        bool oa = (rows.x >= lo) && (rows.x < hi);
        bool ob = (rows.y >= lo) && (rows.y < hi);
        if (oa || ob) {
            float4 ps = *reinterpret_cast<const float4*>(pseudo + 2 * e0);
            int2 cols = *reinterpret_cast<const int2*>(ei + GE + e0);
            if (oa) {
                int p = atomicSub(&cur[rows.x], 1) - 1;
                recs[p] = pack_edge(cols.x, ps.x, ps.y);
            }
            if (ob) {
                int p = atomicSub(&cur[rows.y], 1) - 1;
                recs[p] = pack_edge(cols.y, ps.z, ps.w);
            }
        }
    }
}

// ---------------------------------------------------------------------------
// Gather + fused epilogue; block->node mapping XCD-swizzled to match bucket
// ownership (recs read from the L2 that wrote them).
// ---------------------------------------------------------------------------
__device__ __forceinline__ float edge_term(uint2 r,
                                           const __hip_bfloat16* __restrict__ xw,
                                           int o) {
    unsigned w0 = r.x;
    unsigned col = w0 & 0x1FFFFu;
    int i0 = (w0 >> 17) & 3;
    int i1 = (w0 >> 19) & 3;
    float fr0 = (float)(r.y & 0xFFFFu) * (1.f / 65536.f);
    float fr1 = (float)(r.y >> 16)     * (1.f / 65536.f);
    float g0 = 1.f - fr0, g1 = 1.f - fr1;
    const __hip_bfloat16* base = xw + col * 800u + (unsigned)((i0 + 5 * i1) * 32 + o);
    float v00 = __bfloat162float(base[0]);
    float v01 = __bfloat162float(base[32]);
    float v10 = __bfloat162float(base[160]);
    float v11 = __bfloat162float(base[192]);
    return (g0 * g1) * v00 + (fr0 * g1) * v01 + (g0 * fr1) * v10 + (fr0 * fr1) * v11;
}

__global__ __launch_bounds__(256) void gather_finalize(const uint2* __restrict__ recs,
                                                       const int* __restrict__ offs,
                                                       const __hip_bfloat16* __restrict__ xw,
                                                       const float* __restrict__ X,
                                                       const float* __restrict__ root,
                                                       const float* __restrict__ bias,
                                                       float* __restrict__ out) {
    const int grp = blockIdx.x & (NGRP - 1);
    const int idx = blockIdx.x >> 3;
    const int local = idx * 8 + (threadIdx.x >> 5);
    if (local >= NPG) return;
    const int n = grp * NPG + local;
    const int o = threadIdx.x & 31;

    int start = offs[n];
    int end   = offs[n + 1];

    float a0 = 0.f, a1 = 0.f, a2 = 0.f, a3 = 0.f;
    int j = start;
    for (; j + 4 <= end; j += 4) {
        uint2 r0 = recs[j];
        uint2 r1 = recs[j + 1];
        uint2 r2 = recs[j + 2];
        uint2 r3 = recs[j + 3];
        a0 += edge_term(r0, xw, o);
        a1 += edge_term(r1, xw, o);
        a2 += edge_term(r2, xw, o);
        a3 += edge_term(r3, xw, o);
    }
    for (; j < end; ++j) a0 += edge_term(recs[j], xw, o);
    float acc = (a0 + a1) + (a2 + a3);

    float d = fmaxf((float)(end - start), 1.0f);
    float res = acc / d + bias[o];
    float xv = X[(size_t)n * 32 + o];
#pragma unroll
    for (int i = 0; i < 32; ++i) res += __shfl(xv, i, 32) * root[i * 32 + o];
    out[(size_t)n * 32 + o] = res;
}

// ---------------------------------------------------------------------------
// Fallback path (ws too small): atomic scatter from bf16 xw.
// ---------------------------------------------------------------------------
__global__ __launch_bounds__(256) void edge_scatter(const int* __restrict__ ei,
                                                    const float* __restrict__ pseudo,
                                                    const __hip_bfloat16* __restrict__ xw,
                                                    float* __restrict__ out,
                                                    float* __restrict__ deg) {
    int gid = blockIdx.x * blockDim.x + threadIdx.x;
    int e = gid >> 5;
    int o = gid & 31;
    if (e >= GE) return;
    int row = ei[e];
    int col = ei[GE + e];
    float v0 = pseudo[2 * e] * 4.0f, v1 = pseudo[2 * e + 1] * 4.0f;
    float f0 = floorf(v0), f1 = floorf(v1);
    float fr0 = v0 - f0, fr1 = v1 - f1;
    int i0 = (int)f0, i1 = (int)f1;
    const __hip_bfloat16* base = xw + (size_t)col * GKO + o;
    int w00 = (i0 + 5 * i1) * 32;
    float y = (1.f - fr0) * (1.f - fr1) * __bfloat162float(base[w00])
            + fr0 * (1.f - fr1) * __bfloat162float(base[w00 + 32])
            + (1.f - fr0) * fr1 * __bfloat162float(base[w00 + 160])
            + fr0 * fr1 * __bfloat162float(base[w00 + 192]);
    atomicAdd(&out[(size_t)row * 32 + o], y);
    if (o == 0) atomicAdd(&deg[row], 1.0f);
}

__global__ __launch_bounds__(256) void finalize(const float* __restrict__ X,
                                                const float* __restrict__ root,
                                                const float* __restrict__ bias,
                                                const float* __restrict__ deg,
                                                float* __restrict__ out) {
    int t = blockIdx.x * blockDim.x + threadIdx.x;
    if (t >= GN * 32) return;
    int n = t >> 5, o = t & 31;
    float d = fmaxf(deg[n], 1.0f);
    float acc = out[t] / d + bias[o];
    float xv = X[(size_t)n * 32 + o];
#pragma unroll
    for (int i = 0; i < 32; ++i) acc += __shfl(xv, i, 32) * root[i * 32 + o];
    out[t] = acc;
}

extern "C" void kernel_launch(void* const* d_in, const int* in_sizes, int n_in,
                              void* d_out, int out_size, void* d_ws, size_t ws_size,
                              hipStream_t stream) {
    const float* x      = (const float*)d_in[0];
    const int*   ei     = (const int*)d_in[1];
    const float* pseudo = (const float*)d_in[2];
    const float* weight = (const float*)d_in[3];
    const float* root   = (const float*)d_in[4];
    const float* bias   = (const float*)d_in[5];
    float* out = (float*)d_out;

    const size_t xw_b   = (size_t)GN * GKO * 2;          // 80,000,000
    const size_t rec_b  = (size_t)GE * 8;                // 12,800,000
    const size_t cnt_b  = (size_t)GN * 4;
    const size_t cur_b  = (size_t)GN * 4;
    const size_t offs_b = ((size_t)(GN + 1) * 4 + 15) & ~(size_t)15;
    const size_t bs_b   = (size_t)((SCAN_NB * 4 + 15) & ~15);

    const int gemm_blocks = (GN + 63) / 64;   // 782 (also covers hist: 782*2048 >= GE)

    if (ws_size >= xw_b + rec_b + cnt_b + cur_b + offs_b + 2 * bs_b) {
        char* p = (char*)d_ws;
        __hip_bfloat16* xw = (__hip_bfloat16*)p;  p += xw_b;
        uint2* recs = (uint2*)p;                  p += rec_b;
        int*   cnt  = (int*)p;                    p += cnt_b;
        int*   cur  = (int*)p;                    p += cur_b;
        int*   offs = (int*)p;                    p += offs_b;
        int*   bsum = (int*)p;                    p += bs_b;
        int*   boff = (int*)p;

        hipMemsetAsync(cnt, 0, cnt_b, stream);

        xw_gemm2<<<gemm_blocks, 256, 0, stream>>>(x, weight, xw, ei, cnt);
        scan_a<<<SCAN_NB, 256, 0, stream>>>(cnt, bsum);
        scan_b<<<1, 256, 0, stream>>>(bsum, boff);
        scan_c<<<SCAN_NB, 256, 0, stream>>>(cnt, boff, offs, cur);
        bucket_x<<<NGRP * BPG, 256, 0, stream>>>(ei, pseudo, cur, recs);
        gather_finalize<<<NGRP * ((NPG + 7) / 8), 256, 0, stream>>>(recs, offs, xw, x,
                                                                    root, bias, out);
    } else if (ws_size >= xw_b + (size_t)GN * sizeof(float)) {
        __hip_bfloat16* xw = (__hip_bfloat16*)d_ws;
        float* deg = (float*)((char*)d_ws + xw_b);
        hipMemsetAsync(d_out, 0, (size_t)GN * GOUT * sizeof(float), stream);
        hipMemsetAsync(deg, 0, (size_t)GN * sizeof(float), stream);

        xw_gemm2<<<gemm_blocks, 256, 0, stream>>>(x, weight, xw, nullptr, nullptr);
        edge_scatter<<<(GE * 32 + 255) / 256, 256, 0, stream>>>(ei, pseudo, xw, out, deg);
        finalize<<<(GN * 32 + 255) / 256, 256, 0, stream>>>(x, root, bias, deg, out);
    }
}